// Round 6
// baseline (143.795 us; speedup 1.0000x reference)
//
#include <hip/hip_runtime.h>

#define D 128
#define TM 64

typedef __attribute__((ext_vector_type(8))) short short8v;
typedef __attribute__((ext_vector_type(4))) float float4v;

__device__ __forceinline__ unsigned short f2bf(float f) {
    unsigned int u = __float_as_uint(f);
    u += 0x7FFFu + ((u >> 16) & 1u);   // round-to-nearest-even
    return (unsigned short)(u >> 16);
}
__device__ __forceinline__ float bflo(int u) {
    return __uint_as_float(((unsigned int)u) << 16);
}
__device__ __forceinline__ float bfhi(int u) {
    return __uint_as_float(((unsigned int)u) & 0xFFFF0000u);
}

// Convert 3 weight matrices (each [128][128] fp32, row-major [n][k]) into
// bf16 MFMA B-fragment order:
// dst[((t*4+ks)*64 + lane)*8 + j] = W[t*16+(lane&15)][ks*32+(lane>>4)*8+j]
__global__ __launch_bounds__(256) void wconv(
    const float* __restrict__ w1, const float* __restrict__ w2,
    const float* __restrict__ wb, unsigned short* __restrict__ dst)
{
    int tid = blockIdx.x * 256 + threadIdx.x;   // 0..6143
    int w = tid >> 11;          // which weight
    int r = tid & 2047;         // (t*4+ks)*64 + lane
    int l = r & 63;
    int tk = r >> 6;            // t*4+ks
    int t = tk >> 2, ks = tk & 3;
    int n = t * 16 + (l & 15);
    int k = ks * 32 + (l >> 4) * 8;
    const float* src = (w == 0) ? w1 : (w == 1) ? w2 : wb;
    const float* p = src + n * D + k;
    float4 a = *(const float4*)p;
    float4 b = *(const float4*)(p + 4);
    union { int4 i4; unsigned short u[8]; } pk;
    pk.u[0] = f2bf(a.x); pk.u[1] = f2bf(a.y); pk.u[2] = f2bf(a.z); pk.u[3] = f2bf(a.w);
    pk.u[4] = f2bf(b.x); pk.u[5] = f2bf(b.y); pk.u[6] = f2bf(b.z); pk.u[7] = f2bf(b.w);
    *(int4*)(dst + (size_t)tid * 8) = pk.i4;
}

// Node kernel: R3-proven structure (LDS phase-1, fused GEMM1+2, barrier-free,
// per-wave-private 16-row slices), with 2 LDS buffers instead of 3:
//   phase1: LN(z) -> sa
//   GEMM1+GEMM2 (dual acc) from sa
//   ep1 -> sh ; copyout(sh, T1)
//   ep2 -> sa (overwrite zn; own-wave rows, consumed already)
//   GEMM3 from sa ; out -> sh ; copyout(sh, T2)
__global__ __launch_bounds__(256) void node_kernel(
    const float* __restrict__ z,
    const unsigned short* __restrict__ wfrag,
    const float* __restrict__ lin1_b, const float* __restrict__ lin2_b,
    const float* __restrict__ norm_w, const float* __restrict__ norm_b,
    unsigned short* __restrict__ T1, unsigned short* __restrict__ T2,
    int N)
{
    __shared__ unsigned short sa[TM][136];
    __shared__ unsigned short sh[TM][136];

    const int tid   = threadIdx.x;
    const int lane  = tid & 63;
    const int wave  = tid >> 6;
    const int n0    = blockIdx.x * TM;
    const int cg    = lane & 15;
    const int q     = lane >> 4;
    const int rbase = wave * 16;

    // ---- phase 1: LN(z) -> sa (own 16 rows) ----
    {
        const int c = cg * 8;
        float4 nw0 = *(const float4*)(norm_w + c);
        float4 nw1 = *(const float4*)(norm_w + c + 4);
        float4 nb0 = *(const float4*)(norm_b + c);
        float4 nb1 = *(const float4*)(norm_b + c + 4);
        #pragma unroll
        for (int it = 0; it < 4; ++it) {
            int rr = rbase + it * 4 + q;
            int n  = n0 + rr;
            int nc = (n < N) ? n : (N - 1);
            const float* zp = z + (size_t)nc * D + c;
            float4 v0 = *(const float4*)zp;
            float4 v1 = *(const float4*)(zp + 4);
            float s  = v0.x + v0.y + v0.z + v0.w + v1.x + v1.y + v1.z + v1.w;
            float qq = v0.x*v0.x + v0.y*v0.y + v0.z*v0.z + v0.w*v0.w
                     + v1.x*v1.x + v1.y*v1.y + v1.z*v1.z + v1.w*v1.w;
            #pragma unroll
            for (int m = 1; m <= 8; m <<= 1) {
                s  += __shfl_xor(s, m, 64);
                qq += __shfl_xor(qq, m, 64);
            }
            float mu  = s * (1.0f / D);
            float var = qq * (1.0f / D) - mu * mu;
            float rs  = rsqrtf(var + 1e-5f);
            union { int4 i4; unsigned short u[8]; } pk;
            pk.u[0] = f2bf((v0.x - mu) * rs * nw0.x + nb0.x);
            pk.u[1] = f2bf((v0.y - mu) * rs * nw0.y + nb0.y);
            pk.u[2] = f2bf((v0.z - mu) * rs * nw0.z + nb0.z);
            pk.u[3] = f2bf((v0.w - mu) * rs * nw0.w + nb0.w);
            pk.u[4] = f2bf((v1.x - mu) * rs * nw1.x + nb1.x);
            pk.u[5] = f2bf((v1.y - mu) * rs * nw1.y + nb1.y);
            pk.u[6] = f2bf((v1.z - mu) * rs * nw1.z + nb1.z);
            pk.u[7] = f2bf((v1.w - mu) * rs * nw1.w + nb1.w);
            *(int4*)&sa[rr][c] = pk.i4;
        }
    }

    // ---- GEMM1 + GEMM2 fused (dual accumulators) ----
    float4v acc1[8], acc2[8];
    #pragma unroll
    for (int t = 0; t < 8; ++t) { acc1[t] = (float4v)(0.0f); acc2[t] = (float4v)(0.0f); }
    #pragma unroll
    for (int ks = 0; ks < 4; ++ks) {
        short8v a = *(const short8v*)&sa[rbase + cg][ks * 32 + q * 8];
        const short8v* wp = (const short8v*)wfrag + ks * 64 + lane;
        #pragma unroll
        for (int t = 0; t < 8; ++t) {
            acc1[t] = __builtin_amdgcn_mfma_f32_16x16x32_bf16(a, wp[t * 256],        acc1[t], 0, 0, 0);
            acc2[t] = __builtin_amdgcn_mfma_f32_16x16x32_bf16(a, wp[t * 256 + 2048], acc2[t], 0, 0, 0);
        }
    }

    // bias+relu+LN epilogue (C-layout: col=t*16+cg, row=rbase+q*4+i) -> dst
    auto epilogue = [&](float4v* acc, const float* lb, unsigned short (*dst)[136]) {
        float s[4] = {0, 0, 0, 0}, qs[4] = {0, 0, 0, 0};
        #pragma unroll
        for (int t = 0; t < 8; ++t) {
            float b = lb[t * 16 + cg];
            #pragma unroll
            for (int i = 0; i < 4; ++i) {
                float v = fmaxf(acc[t][i] + b, 0.0f);
                acc[t][i] = v;
                s[i] += v; qs[i] += v * v;
            }
        }
        #pragma unroll
        for (int i = 0; i < 4; ++i) {
            #pragma unroll
            for (int m = 1; m <= 8; m <<= 1) {
                s[i]  += __shfl_xor(s[i], m, 64);
                qs[i] += __shfl_xor(qs[i], m, 64);
            }
            float mu  = s[i] * (1.0f / D);
            float var = qs[i] * (1.0f / D) - mu * mu;
            s[i] = mu; qs[i] = rsqrtf(var + 1e-5f);
        }
        #pragma unroll
        for (int t = 0; t < 8; ++t) {
            int col = t * 16 + cg;
            float nw = norm_w[col], nb = norm_b[col];
            #pragma unroll
            for (int i = 0; i < 4; ++i)
                dst[rbase + q * 4 + i][col] = f2bf((acc[t][i] - s[i]) * qs[i] * nw + nb);
        }
    };

    // coalesced LDS -> global bf16 copy of own 16 rows
    auto copyout = [&](const unsigned short (*S)[136], unsigned short* dst) {
        int r = tid >> 2;
        int n = n0 + r;
        if (n < N) {
            #pragma unroll
            for (int j = 0; j < 4; ++j) {
                int c = (tid & 3) * 8 + j * 32;
                *(int4*)(dst + (size_t)n * D + c) = *(const int4*)&S[r][c];
            }
        }
    };

    epilogue(acc1, lin1_b, sh);
    copyout(sh, T1);
    epilogue(acc2, lin2_b, sa);     // overwrite zn rows (own wave, already consumed)

    // ---- GEMM3: T2 = H2 @ Wb^T (A from sa) ----
    #pragma unroll
    for (int t = 0; t < 8; ++t) acc1[t] = (float4v)(0.0f);
    #pragma unroll
    for (int ks = 0; ks < 4; ++ks) {
        short8v a = *(const short8v*)&sa[rbase + cg][ks * 32 + q * 8];
        const short8v* wp = (const short8v*)wfrag + 4096 + ks * 64 + lane;
        #pragma unroll
        for (int t = 0; t < 8; ++t)
            acc1[t] = __builtin_amdgcn_mfma_f32_16x16x32_bf16(a, wp[t * 256], acc1[t], 0, 0, 0);
    }
    #pragma unroll
    for (int t = 0; t < 8; ++t)
        #pragma unroll
        for (int i = 0; i < 4; ++i)
            sh[rbase + q * 4 + i][t * 16 + cg] = f2bf(acc1[t][i]);
    copyout(sh, T2);
}

// score[e] = dot(T1[a0], T2[a1]) + bb ; 4 lanes/arc, 2 arcs/thread,
// 32 arcs/wave: 16 independent 16B gathers per lane for MLP.
__global__ __launch_bounds__(256) void arc_kernel(
    const int* __restrict__ arcs,
    const unsigned short* __restrict__ T1,
    const unsigned short* __restrict__ T2,
    const float* __restrict__ bil_b,
    float* __restrict__ out, int E)
{
    const int tid  = threadIdx.x;
    const int lane = tid & 63;
    long long gw = ((long long)blockIdx.x * 256 + tid) >> 6;   // global wave id
    long long e0 = gw * 32;
    int aidx = lane >> 2;          // arc slot within half-wave (0..15)
    int s    = lane & 3;           // lane within arc

    long long ii = e0 * 2 + lane;  // 64 ints = indices of 32 arcs
    long long iimax = (long long)E * 2 - 1;
    int iv = arcs[ii <= iimax ? ii : iimax];
    int a0A = __shfl(iv, aidx * 2, 64);
    int a1A = __shfl(iv, aidx * 2 + 1, 64);
    int a0B = __shfl(iv, 32 + aidx * 2, 64);
    int a1B = __shfl(iv, 32 + aidx * 2 + 1, 64);
    long long eA = e0 + aidx;
    long long eB = e0 + 16 + aidx;

    const int4* PA = (const int4*)(T1 + (size_t)a0A * D);
    const int4* QA = (const int4*)(T2 + (size_t)a1A * D);
    const int4* PB = (const int4*)(T1 + (size_t)a0B * D);
    const int4* QB = (const int4*)(T2 + (size_t)a1B * D);
    int4 xa0 = PA[s], xa1 = PA[s + 4], xa2 = PA[s + 8], xa3 = PA[s + 12];
    int4 ya0 = QA[s], ya1 = QA[s + 4], ya2 = QA[s + 8], ya3 = QA[s + 12];
    int4 xb0 = PB[s], xb1 = PB[s + 4], xb2 = PB[s + 8], xb3 = PB[s + 12];
    int4 yb0 = QB[s], yb1 = QB[s + 4], yb2 = QB[s + 8], yb3 = QB[s + 12];

    #define DOT4(a, b) (bflo(a.x)*bflo(b.x) + bfhi(a.x)*bfhi(b.x) + \
                        bflo(a.y)*bflo(b.y) + bfhi(a.y)*bfhi(b.y) + \
                        bflo(a.z)*bflo(b.z) + bfhi(a.z)*bfhi(b.z) + \
                        bflo(a.w)*bflo(b.w) + bfhi(a.w)*bfhi(b.w))

    float accA = 0.0f, accB = 0.0f;
    accA += DOT4(xa0, ya0); accA += DOT4(xa1, ya1);
    accA += DOT4(xa2, ya2); accA += DOT4(xa3, ya3);
    accB += DOT4(xb0, yb0); accB += DOT4(xb1, yb1);
    accB += DOT4(xb2, yb2); accB += DOT4(xb3, yb3);
    #undef DOT4

    accA += __shfl_xor(accA, 1, 64);
    accA += __shfl_xor(accA, 2, 64);
    accB += __shfl_xor(accB, 1, 64);
    accB += __shfl_xor(accB, 2, 64);

    if (s == 0) {
        float bb = bil_b[0];
        if (eA < E) out[eA] = accA + bb;
        if (eB < E) out[eB] = accB + bb;
    }
}

extern "C" void kernel_launch(void* const* d_in, const int* in_sizes, int n_in,
                              void* d_out, int out_size, void* d_ws, size_t ws_size,
                              hipStream_t stream) {
    const float* z      = (const float*)d_in[0];
    const int*   arcs   = (const int*)d_in[1];
    const float* lin1_w = (const float*)d_in[2];
    const float* lin1_b = (const float*)d_in[3];
    const float* lin2_w = (const float*)d_in[4];
    const float* lin2_b = (const float*)d_in[5];
    const float* bil_w  = (const float*)d_in[6];
    const float* bil_b  = (const float*)d_in[7];
    const float* norm_w = (const float*)d_in[8];
    const float* norm_b = (const float*)d_in[9];
    float* out = (float*)d_out;

    const int N = in_sizes[0] / D;
    const int E = in_sizes[1] / 2;

    unsigned short* wfrag = (unsigned short*)d_ws;          // 3 * 16384 shorts
    unsigned short* T1 = wfrag + 3 * 16384;
    unsigned short* T2 = T1 + (size_t)N * D;

    wconv<<<24, 256, 0, stream>>>(lin1_w, lin2_w, bil_w, wfrag);

    node_kernel<<<(N + TM - 1) / TM, 256, 0, stream>>>(
        z, wfrag, lin1_b, lin2_b, norm_w, norm_b, T1, T2, N);

    long long waves = ((long long)E + 31) / 32;
    int blocks = (int)((waves + 3) / 4);
    arc_kernel<<<blocks, 256, 0, stream>>>(arcs, T1, T2, bil_b, out, E);
}